// Round 4
// baseline (323.597 us; speedup 1.0000x reference)
//
#include <hip/hip_runtime.h>

// LinearAttention fused, R4: barrier-free wave-private MFMA pipeline.
//   kZ: zero ctx/Z accumulators + convert w_qkv to bf16
//   kA: LN1 -> k,v GEMM -> exp(k) -> ctx += ek @ v^T (+ ones-col MFMA for Z)
//       -> cross-wave reduce -> spread atomicAdd
//   kM: M[b,h,o,dd] = sum_e wout[o,h*32+e] * ctx[b,h,dd,e]/Z[b,h,dd]  (bf16)
//   kB: LN1 -> q GEMM -> shfl softmax -> shfl transpose -> y = M @ qs -> LN2
//   R4 fix: kB waves now cover nt=0..3 (64 cols/wave, 128/block); R3 only did 32.
#define NCOL 131072
#define CH 64

typedef float floatx4 __attribute__((ext_vector_type(4)));
typedef __bf16 bf16x8 __attribute__((ext_vector_type(8)));
typedef unsigned int u32x4 __attribute__((ext_vector_type(4)));

union FragU { u32x4 q; bf16x8 v; unsigned short us[8]; unsigned ud[4]; };

__device__ __forceinline__ unsigned short f2bf(float f){
  union { float f; unsigned u; } x{f};
  unsigned r = x.u + 0x7fffu + ((x.u >> 16) & 1u);
  return (unsigned short)(r >> 16);
}
__device__ __forceinline__ unsigned packbf(float a, float b){
  return (unsigned)f2bf(a) | ((unsigned)f2bf(b) << 16);
}

// LN over 64 channels for one column; writes bf16 column (64 ch) at dst
__device__ __forceinline__ void ln_stage(const float* __restrict__ xp,
    const float* __restrict__ g, const float* __restrict__ bb,
    unsigned short* __restrict__ dst)
{
  float xv[64]; float s = 0.f, ss = 0.f;
  #pragma unroll
  for (int c = 0; c < 64; c++){ float u = xp[(long)c*NCOL]; xv[c] = u; s += u; ss = fmaf(u,u,ss); }
  const float mean = s * (1.f/64.f);
  const float rstd = rsqrtf(ss * (1.f/64.f) - mean*mean + 1e-5f);
  #pragma unroll
  for (int c = 0; c < 64; c++) xv[c] = (xv[c]-mean)*rstd*g[c] + bb[c];
  #pragma unroll
  for (int j = 0; j < 8; j++){
    FragU u;
    #pragma unroll
    for (int e = 0; e < 4; e++) u.ud[e] = packbf(xv[j*8+2*e], xv[j*8+2*e+1]);
    *(u32x4*)(dst + j*8) = u.q;
  }
}

// ---------------- kZ: zero accumulators + wqkv->bf16 ----------------
__global__ __launch_bounds__(256) void kZ(const float* __restrict__ wqkv,
    float* __restrict__ ws_f, unsigned short* __restrict__ wb)
{
  const int idx = blockIdx.x*256 + threadIdx.x;
  if (idx < 135168) ws_f[idx] = 0.f;
  else { const int j = idx - 135168; if (j < 24576) wb[j] = f2bf(wqkv[j]); }
}

// ---------------- kA ----------------
__global__ __launch_bounds__(256) void kA(
    const float* __restrict__ x, const float* __restrict__ g1, const float* __restrict__ b1,
    const unsigned short* __restrict__ wb, float* __restrict__ ctx_a, float* __restrict__ Zg)
{
  __shared__ __align__(16) char smem[38912];
  float* lds_f = (float*)smem;
  const int t = threadIdx.x, bid = blockIdx.x;
  const int b = bid >> 8, cpair = bid & 255;
  const int w = t >> 6, lane = t & 63, qq = lane >> 4, l16 = lane & 15;
  char* wreg = smem + w*9216;                              // wave-private region
  unsigned short* xn_s = (unsigned short*)wreg;            // [64 col][72] (aliased below)
  unsigned short* ek_s = (unsigned short*)wreg;            // [32 d][72]
  unsigned short* v_s  = (unsigned short*)(wreg + 4608);   // [32 e][72]

  // zero Zp[w][4][32] (wave-private)
  lds_f[9216 + w*128 + lane] = 0.f;
  lds_f[9216 + w*128 + 64 + lane] = 0.f;

  floatx4 cc[4][2][2];
  #pragma unroll
  for (int h = 0; h < 4; h++)
    #pragma unroll
    for (int dt = 0; dt < 2; dt++)
      #pragma unroll
      for (int et = 0; et < 2; et++) cc[h][dt][et] = floatx4{0.f,0.f,0.f,0.f};

  const unsigned onesv = (l16 == 0) ? 0x3F803F80u : 0u;
  FragU bone; bone.ud[0] = onesv; bone.ud[1] = onesv; bone.ud[2] = onesv; bone.ud[3] = onesv;

  for (int ck = 0; ck < 2; ck++){
    const long col0 = ((long)cpair*2 + ck) * 256;
    ln_stage(x + (long)b*CH*NCOL + col0 + t, g1, b1, xn_s + lane*72);

    FragU bx[4][2];
    #pragma unroll
    for (int nt = 0; nt < 4; nt++)
      #pragma unroll
      for (int ks = 0; ks < 2; ks++)
        bx[nt][ks].q = *(const u32x4*)(xn_s + (nt*16 + l16)*72 + ks*32 + qq*8);

    #pragma unroll
    for (int h = 0; h < 4; h++){
      FragU ak[2][2], av[2][2];
      #pragma unroll
      for (int rt = 0; rt < 2; rt++)
        #pragma unroll
        for (int ks = 0; ks < 2; ks++){
          ak[rt][ks].q = *(const u32x4*)(wb + (128 + h*32 + rt*16 + l16)*64 + ks*32 + qq*8);
          av[rt][ks].q = *(const u32x4*)(wb + (256 + h*32 + rt*16 + l16)*64 + ks*32 + qq*8);
        }
      #pragma unroll
      for (int rt = 0; rt < 2; rt++)
        #pragma unroll
        for (int nt = 0; nt < 4; nt++){
          floatx4 c = floatx4{0.f,0.f,0.f,0.f};
          c = __builtin_amdgcn_mfma_f32_16x16x32_bf16(ak[rt][0].v, bx[nt][0].v, c, 0, 0, 0);
          c = __builtin_amdgcn_mfma_f32_16x16x32_bf16(ak[rt][1].v, bx[nt][1].v, c, 0, 0, 0);
          #pragma unroll
          for (int r = 0; r < 4; r++) ek_s[(rt*16 + qq*4 + r)*72 + nt*16 + l16] = f2bf(__expf(c[r]));
          floatx4 cv = floatx4{0.f,0.f,0.f,0.f};
          cv = __builtin_amdgcn_mfma_f32_16x16x32_bf16(av[rt][0].v, bx[nt][0].v, cv, 0, 0, 0);
          cv = __builtin_amdgcn_mfma_f32_16x16x32_bf16(av[rt][1].v, bx[nt][1].v, cv, 0, 0, 0);
          #pragma unroll
          for (int r = 0; r < 4; r++) v_s[(rt*16 + qq*4 + r)*72 + nt*16 + l16] = f2bf(cv[r]);
        }
      floatx4 cz[2] = {floatx4{0.f,0.f,0.f,0.f}, floatx4{0.f,0.f,0.f,0.f}};
      #pragma unroll
      for (int kk = 0; kk < 2; kk++){
        FragU ae[2], bv[2];
        #pragma unroll
        for (int dt = 0; dt < 2; dt++) ae[dt].q = *(const u32x4*)(ek_s + (dt*16 + l16)*72 + kk*32 + qq*8);
        #pragma unroll
        for (int et = 0; et < 2; et++) bv[et].q = *(const u32x4*)(v_s  + (et*16 + l16)*72 + kk*32 + qq*8);
        #pragma unroll
        for (int dt = 0; dt < 2; dt++){
          #pragma unroll
          for (int et = 0; et < 2; et++)
            cc[h][dt][et] = __builtin_amdgcn_mfma_f32_16x16x32_bf16(ae[dt].v, bv[et].v, cc[h][dt][et], 0, 0, 0);
          cz[dt] = __builtin_amdgcn_mfma_f32_16x16x32_bf16(ae[dt].v, bone.v, cz[dt], 0, 0, 0);
        }
      }
      if (l16 == 0){
        #pragma unroll
        for (int dt = 0; dt < 2; dt++){
          float* p = lds_f + 9216 + w*128 + h*32 + dt*16 + qq*4;
          floatx4 old = *(floatx4*)p;
          old += cz[dt];
          *(floatx4*)p = old;
        }
      }
    }
  }

  // cross-wave reduce (2 passes of 8192 floats) + spread atomics
  const int lane_r = t >> 2, rr = t & 3;
  const int q2 = lane_r >> 4, c2 = lane_r & 15;
  __syncthreads();
  #pragma unroll
  for (int p = 0; p < 2; p++){
    #pragma unroll
    for (int dh = 0; dh < 2; dh++)
      #pragma unroll
      for (int dt = 0; dt < 2; dt++)
        #pragma unroll
        for (int et = 0; et < 2; et++)
          *(floatx4*)(lds_f + w*2048 + (dh*4 + dt*2 + et)*256 + lane*4) = cc[p*2+dh][dt][et];
    __syncthreads();
    #pragma unroll
    for (int i = 0; i < 8; i++){
      const int j = i*256 + t;
      const float v = lds_f[j] + lds_f[2048+j] + lds_f[4096+j] + lds_f[6144+j];
      const int dh = i >> 2, dt = (i >> 1) & 1, et = i & 1;
      const int h = p*2 + dh, d = dt*16 + q2*4 + rr, e = et*16 + c2;
      atomicAdd(&ctx_a[((((long)b*4 + h)*32 + d)*32 + e)*16], v);
    }
    __syncthreads();
  }
  if (t < 128){
    const int h = t >> 5, dd = t & 31;
    float z = 0.f;
    #pragma unroll
    for (int ww = 0; ww < 4; ww++) z += lds_f[9216 + ww*128 + h*32 + dd];
    atomicAdd(&Zg[(((long)b*4 + h)*32 + dd)*16], z);
  }
}

// ---------------- kM: normalize ctx + fuse w_out -> bf16 M ----------------
__global__ __launch_bounds__(256) void kM(
    const float* __restrict__ ctx_a, const float* __restrict__ Zg,
    const float* __restrict__ wout, unsigned short* __restrict__ Mb)
{
  const int idx = blockIdx.x*256 + threadIdx.x;  // 16384 = [b][h][o][dd]
  const int dd = idx & 31, o = (idx >> 5) & 63, h = (idx >> 11) & 3, b = idx >> 13;
  const float z = Zg[(((long)b*4 + h)*32 + dd)*16];
  const float* wrow = wout + o*128 + h*32;
  const float* crow = ctx_a + ((((long)b*4 + h)*32 + dd)*32)*16;
  float acc = 0.f;
  #pragma unroll
  for (int e = 0; e < 32; e++) acc = fmaf(wrow[e], crow[e*16], acc);
  Mb[idx] = f2bf(acc / z);
}

// ---------------- kB ----------------
__global__ __launch_bounds__(128) void kB(
    const float* __restrict__ x, const float* __restrict__ g1, const float* __restrict__ b1,
    const unsigned short* __restrict__ wb, const unsigned short* __restrict__ Mb,
    const float* __restrict__ bout, const float* __restrict__ g2, const float* __restrict__ b2,
    float* __restrict__ y)
{
  __shared__ __align__(16) unsigned short xn_s[128*72];
  const int t = threadIdx.x, bid = blockIdx.x;
  const int b = bid >> 10;
  const long col0 = (long)(bid & 1023) * 128;
  const int w = t >> 6, lane = t & 63, qq = lane >> 4, l16 = lane & 15;

  ln_stage(x + (long)b*CH*NCOL + col0 + t, g1, b1, xn_s + t*72);

  FragU bx[4][2];
  #pragma unroll
  for (int nt = 0; nt < 4; nt++)
    #pragma unroll
    for (int ks = 0; ks < 2; ks++)
      bx[nt][ks].q = *(const u32x4*)(xn_s + (w*64 + nt*16 + l16)*72 + ks*32 + qq*8);

  floatx4 yacc[4][4];
  #pragma unroll
  for (int ot = 0; ot < 4; ot++)
    #pragma unroll
    for (int nt = 0; nt < 4; nt++) yacc[ot][nt] = floatx4{0.f,0.f,0.f,0.f};

  const int src0 = ((qq & 1) << 5) + l16;   // source lane: quad 2*(qq&1), same n
  const int src1 = src0 + 16;
  const bool hi = (qq >= 2);

  #pragma unroll
  for (int h = 0; h < 4; h++){
    FragU aq[2][2], am[4];
    #pragma unroll
    for (int ot = 0; ot < 2; ot++)
      #pragma unroll
      for (int ks = 0; ks < 2; ks++)
        aq[ot][ks].q = *(const u32x4*)(wb + (h*32 + ot*16 + l16)*64 + ks*32 + qq*8);
    #pragma unroll
    for (int ot = 0; ot < 4; ot++)
      am[ot].q = *(const u32x4*)(Mb + (((long)b*4 + h)*64 + ot*16 + l16)*32 + qq*8);

    #pragma unroll
    for (int nt = 0; nt < 4; nt++){
      float ev[2][4];
      #pragma unroll
      for (int ot = 0; ot < 2; ot++){
        floatx4 c = floatx4{0.f,0.f,0.f,0.f};
        c = __builtin_amdgcn_mfma_f32_16x16x32_bf16(aq[ot][0].v, bx[nt][0].v, c, 0, 0, 0);
        c = __builtin_amdgcn_mfma_f32_16x16x32_bf16(aq[ot][1].v, bx[nt][1].v, c, 0, 0, 0);
        #pragma unroll
        for (int r = 0; r < 4; r++) ev[ot][r] = __expf(c[r]);
      }
      float s = 0.f;
      #pragma unroll
      for (int r = 0; r < 4; r++) s += ev[0][r] + ev[1][r];
      s += __shfl_xor(s, 16, 64);
      s += __shfl_xor(s, 32, 64);
      const float sc = 0.17677669529663687f / s;   // 32^-0.5 / sum
      const unsigned pd00 = packbf(ev[0][0]*sc, ev[0][1]*sc);
      const unsigned pd01 = packbf(ev[0][2]*sc, ev[0][3]*sc);
      const unsigned pd10 = packbf(ev[1][0]*sc, ev[1][1]*sc);
      const unsigned pd11 = packbf(ev[1][2]*sc, ev[1][3]*sc);
      FragU bq;
      unsigned a0, a1;
      a0 = (unsigned)__shfl((int)pd00, src0, 64); a1 = (unsigned)__shfl((int)pd10, src0, 64);
      bq.ud[0] = hi ? a1 : a0;
      a0 = (unsigned)__shfl((int)pd01, src0, 64); a1 = (unsigned)__shfl((int)pd11, src0, 64);
      bq.ud[1] = hi ? a1 : a0;
      a0 = (unsigned)__shfl((int)pd00, src1, 64); a1 = (unsigned)__shfl((int)pd10, src1, 64);
      bq.ud[2] = hi ? a1 : a0;
      a0 = (unsigned)__shfl((int)pd01, src1, 64); a1 = (unsigned)__shfl((int)pd11, src1, 64);
      bq.ud[3] = hi ? a1 : a0;

      #pragma unroll
      for (int ot = 0; ot < 4; ot++)
        yacc[ot][nt] = __builtin_amdgcn_mfma_f32_16x16x32_bf16(am[ot].v, bq.v, yacc[ot][nt], 0, 0, 0);
    }
  }

  // epilogue: +b_out, LN2, store
  const long ybase = (long)b*CH*NCOL;
  #pragma unroll
  for (int nt = 0; nt < 4; nt++){
    const long colg = col0 + w*64 + nt*16 + l16;
    float vals[16]; float s = 0.f, ss = 0.f;
    #pragma unroll
    for (int ot = 0; ot < 4; ot++)
      #pragma unroll
      for (int r = 0; r < 4; r++){
        const float v = yacc[ot][nt][r] + bout[ot*16 + qq*4 + r];
        vals[ot*4+r] = v; s += v; ss = fmaf(v, v, ss);
      }
    s  += __shfl_xor(s, 16, 64);  s  += __shfl_xor(s, 32, 64);
    ss += __shfl_xor(ss, 16, 64); ss += __shfl_xor(ss, 32, 64);
    const float mean = s * (1.f/64.f);
    const float rstd = rsqrtf(ss * (1.f/64.f) - mean*mean + 1e-5f);
    #pragma unroll
    for (int ot = 0; ot < 4; ot++)
      #pragma unroll
      for (int r = 0; r < 4; r++){
        const int row = ot*16 + qq*4 + r;
        y[ybase + (long)row*NCOL + colg] = (vals[ot*4+r]-mean)*rstd*g2[row] + b2[row];
      }
  }
}

extern "C" void kernel_launch(void* const* d_in, const int* in_sizes, int n_in,
                              void* d_out, int out_size, void* d_ws, size_t ws_size,
                              hipStream_t stream)
{
  const float* x    = (const float*)d_in[0];
  const float* g1   = (const float*)d_in[1];
  const float* b1   = (const float*)d_in[2];
  const float* wqkv = (const float*)d_in[3];
  const float* wout = (const float*)d_in[4];
  const float* bout = (const float*)d_in[5];
  const float* g2   = (const float*)d_in[6];
  const float* b2   = (const float*)d_in[7];
  float* y  = (float*)d_out;
  float* ws_f = (float*)d_ws;

  float* ctx_a = ws_f;                                   // 131072 floats (pad x16)
  float* Zg    = ws_f + 131072;                          //   4096 floats (pad x16)
  unsigned short* wb = (unsigned short*)(ws_f + 135168); //  24576 bf16
  unsigned short* Mb = (unsigned short*)(ws_f + 147456); //  16384 bf16

  hipLaunchKernelGGL(kZ, dim3(624),  dim3(256), 0, stream, wqkv, ws_f, wb);
  hipLaunchKernelGGL(kA, dim3(512),  dim3(256), 0, stream, x, g1, b1, wb, ctx_a, Zg);
  hipLaunchKernelGGL(kM, dim3(64),   dim3(256), 0, stream, ctx_a, Zg, wout, Mb);
  hipLaunchKernelGGL(kB, dim3(2048), dim3(128), 0, stream, x, g1, b1, wb, Mb, bout, g2, b2, y);
}